// Round 7
// baseline (445.061 us; speedup 1.0000x reference)
//
#include <hip/hip_runtime.h>
#include <math.h>

// Problem constants (match reference)
#define NB   64     // num_groups (B)
#define NG   32     // group_size (G)
#define ND   2000   // output dim D
#define NM   16     // m_samples
#define NE   16     // noise dim
#define NDIN 256
#define NK   272    // DIN + E

// ---------------------------------------------------------------------------
// Round-7, from r6 profile (mega 240us + ~174us unattributed tail):
//  - mega per-iter: LDS 262KB (1.3us) vs L2-stream 250KB (1.7us) -> stream
//    is the longer pipe.  Rebalance: 1216 cols LDS (157.7KB, r3 proved
//    159.7KB launches), 784 streamed (-23% stream traffic).
//  - k_epi rewrite: rank loops were ~4000 ds_read_b32/thread (DS-pipe
//    bound).  Register-resident instead: in-place c32[32] (col->z->frac,
//    one static array) + yv PACKED 4 bytes/dword in 8 VGPRs -> live ~55
//    regs, fits the allocator's proven 64-84 budget (r4 spill trap dead
//    by construction).  One col/thread, 128K threads, ~3kcyc/thread
//    => ~5us VALU full-chip + ~5us L2 re-read.
//  - B finals parked as 8 replicas at 250-col boundaries so each k_epi
//    block reads A/B only from its OWN range before overwriting.
// ---------------------------------------------------------------------------
#define XPT_COLS 1216                       // cols 0..1215 in xpT (LDS class)
#define SP_COLS  784                        // cols 1216..1999 streamed
#define SP_TAU   196                        // SP_COLS/4
#define SP_STRIDE4 6272                     // float4 per b: 4*8*196
#define SMEM_MEGA (2048 + XPT_COLS * 128)   // 2KB wred + 155.6KB cols = 157696

__device__ __forceinline__ float clampf(float v, float lo, float hi) {
    return fminf(fmaxf(v, lo), hi);
}

__device__ __forceinline__ float softplusf(float v) {
    return (v > 20.f) ? v : log1pf(expf(v));
}

__device__ __forceinline__ float readlane_f(float v, int lane) {
    return __int_as_float(__builtin_amdgcn_readlane(__float_as_int(v), lane));
}

// streamP float4 index within one b: [cj][k][tau] -> lanes (consecutive tau)
// read consecutive float4 for fixed (cj,k) = coalesced.
__device__ __forceinline__ int sp_idx(int tau, int cj, int k) {
    return (cj * 8 + k) * SP_TAU + tau;
}

// packed-byte yv helpers (g is always a compile-time constant after unroll)
__device__ __forceinline__ int yget(const int* yvp, int g) {
    return (yvp[g >> 2] >> (8 * (g & 3))) & 0xff;
}
__device__ __forceinline__ void yadd(int* yvp, int g, int delta) {
    yvp[g >> 2] += delta << (8 * (g & 3));
}

// Fully-packed butterfly: reduce v[0..31] (per-g partials) across 64 lanes in
// 32 shuffles.  Returns the wave total for g = (lane>>1)&31 (dup on pairs).
__device__ __forceinline__ float wave_sum32(float v[NG], int lane) {
    {   const bool hi = (lane & 32) != 0;
        #pragma unroll
        for (int k = 0; k < 16; ++k) {
            float s = hi ? v[k] : v[k + 16];
            float r = __shfl_xor(s, 32);
            v[k] = (hi ? v[k + 16] : v[k]) + r;
        }
    }
    {   const bool hi = (lane & 16) != 0;
        #pragma unroll
        for (int k = 0; k < 8; ++k) {
            float s = hi ? v[k] : v[k + 8];
            float r = __shfl_xor(s, 16);
            v[k] = (hi ? v[k + 8] : v[k]) + r;
        }
    }
    {   const bool hi = (lane & 8) != 0;
        #pragma unroll
        for (int k = 0; k < 4; ++k) {
            float s = hi ? v[k] : v[k + 4];
            float r = __shfl_xor(s, 8);
            v[k] = (hi ? v[k + 4] : v[k]) + r;
        }
    }
    {   const bool hi = (lane & 4) != 0;
        #pragma unroll
        for (int k = 0; k < 2; ++k) {
            float s = hi ? v[k] : v[k + 2];
            float r = __shfl_xor(s, 4);
            v[k] = (hi ? v[k + 2] : v[k]) + r;
        }
    }
    {   const bool hi = (lane & 2) != 0;
        float s = hi ? v[0] : v[1];
        float r = __shfl_xor(s, 2);
        v[0] = (hi ? v[1] : v[0]) + r;
    }
    v[0] += __shfl_xor(v[0], 1);
    return v[0];
}

// ---- IPF path: 512 thr, thread owns cols 4t..4t+3 (r6 structure) ---------
__device__ __forceinline__ void ipf_path(
        const float* __restrict__ xpT, const float* __restrict__ spB,
        const int* __restrict__ tsum, float* __restrict__ out,
        char* smem, int b, int t) {
    const int lane = t & 63, w = t >> 6;       // 8 waves
    const int c0 = 4 * t;
    const bool valid = (t < 500);
    const bool lcls  = (t < 304);              // cols in LDS (1216 cols)
    const int g_own = (lane >> 1) & 31;
    const int rot = t & 7;
    const int tau = t - 304;

    float* wred = (float*)smem;                // [2][8][32] dbuf
    char* cbase = smem + 2048 + (size_t)c0 * 128;   // 4 slots x 128B (lcls)
    const float4* gx = (const float4*)(xpT + ((size_t)b * XPT_COLS + c0) * NG);
    const float4* gs = (const float4*)spB + (size_t)b * SP_STRIDE4;

    float Cc[4] = {0.f, 0.f, 0.f, 0.f};
    if (valid) {
        const int4 ci = *(const int4*)(tsum + (size_t)b * ND + c0);
        Cc[0] = (float)ci.x; Cc[1] = (float)ci.y;
        Cc[2] = (float)ci.z; Cc[3] = (float)ci.w;
    }
    float Ac[4] = {1.f, 1.f, 1.f, 1.f};
    float Bown = 1.f, Rown;

    // prologue: load 4 cols, stash LDS-class, row anchors R
    {
        float v[NG];
        if (lcls) {
            #pragma unroll
            for (int k = 0; k < 8; ++k) {
                const float4 a = gx[k], e = gx[8 + k], f = gx[16 + k], h = gx[24 + k];
                const int ro = 16 * ((k + rot) & 7);
                *(float4*)(cbase + ro)       = a;
                *(float4*)(cbase + 128 + ro) = e;
                *(float4*)(cbase + 256 + ro) = f;
                *(float4*)(cbase + 384 + ro) = h;
                v[4*k+0] = ((a.x + e.x) + f.x) + h.x;
                v[4*k+1] = ((a.y + e.y) + f.y) + h.y;
                v[4*k+2] = ((a.z + e.z) + f.z) + h.z;
                v[4*k+3] = ((a.w + e.w) + f.w) + h.w;
            }
        } else if (valid) {
            #pragma unroll
            for (int k = 0; k < 8; ++k) {
                const float4 a = gs[sp_idx(tau, 0, k)];
                const float4 e = gs[sp_idx(tau, 1, k)];
                const float4 f = gs[sp_idx(tau, 2, k)];
                const float4 h = gs[sp_idx(tau, 3, k)];
                v[4*k+0] = ((a.x + e.x) + f.x) + h.x;
                v[4*k+1] = ((a.y + e.y) + f.y) + h.y;
                v[4*k+2] = ((a.z + e.z) + f.z) + h.z;
                v[4*k+3] = ((a.w + e.w) + f.w) + h.w;
            }
        } else {
            #pragma unroll
            for (int g = 0; g < NG; ++g) v[g] = 0.f;
        }
        const float tot = wave_sum32(v, lane);
        if (!(lane & 1)) wred[w * NG + g_own] = tot;
        __syncthreads();
        float s = 0.f;
        #pragma unroll
        for (int w2 = 0; w2 < 8; ++w2) s += wred[w2 * NG + g_own];
        Rown = s;
    }

    // 60 IPF iterations, one barrier each (dbuf wred), NO cross-block sync
    for (int q = 1; q <= 60; ++q) {
        float s0 = 0.f, s1 = 0.f, s2 = 0.f, s3 = 0.f;
        if (lcls) {
            #pragma unroll
            for (int k = 0; k < 8; ++k) {
                const int ro = 16 * ((k + rot) & 7);
                const float4 a = *(const float4*)(cbase + ro);
                const float4 e = *(const float4*)(cbase + 128 + ro);
                const float4 f = *(const float4*)(cbase + 256 + ro);
                const float4 h = *(const float4*)(cbase + 384 + ro);
                float bg;
                bg = readlane_f(Bown, 8*k+0); s0 += a.x*bg; s1 += e.x*bg; s2 += f.x*bg; s3 += h.x*bg;
                bg = readlane_f(Bown, 8*k+2); s0 += a.y*bg; s1 += e.y*bg; s2 += f.y*bg; s3 += h.y*bg;
                bg = readlane_f(Bown, 8*k+4); s0 += a.z*bg; s1 += e.z*bg; s2 += f.z*bg; s3 += h.z*bg;
                bg = readlane_f(Bown, 8*k+6); s0 += a.w*bg; s1 += e.w*bg; s2 += f.w*bg; s3 += h.w*bg;
            }
        } else if (valid) {
            #pragma unroll
            for (int k = 0; k < 8; ++k) {
                const float4 a = gs[sp_idx(tau, 0, k)];
                const float4 e = gs[sp_idx(tau, 1, k)];
                const float4 f = gs[sp_idx(tau, 2, k)];
                const float4 h = gs[sp_idx(tau, 3, k)];
                float bg;
                bg = readlane_f(Bown, 8*k+0); s0 += a.x*bg; s1 += e.x*bg; s2 += f.x*bg; s3 += h.x*bg;
                bg = readlane_f(Bown, 8*k+2); s0 += a.y*bg; s1 += e.y*bg; s2 += f.y*bg; s3 += h.y*bg;
                bg = readlane_f(Bown, 8*k+4); s0 += a.z*bg; s1 += e.z*bg; s2 += f.z*bg; s3 += h.z*bg;
                bg = readlane_f(Bown, 8*k+6); s0 += a.w*bg; s1 += e.w*bg; s2 += f.w*bg; s3 += h.w*bg;
            }
        }
        Ac[0] *= clampf(Cc[0] / fmaxf(Ac[0] * s0, 1e-12f), 0.75f, 1.25f);
        Ac[1] *= clampf(Cc[1] / fmaxf(Ac[1] * s1, 1e-12f), 0.75f, 1.25f);
        Ac[2] *= clampf(Cc[2] / fmaxf(Ac[2] * s2, 1e-12f), 0.75f, 1.25f);
        Ac[3] *= clampf(Cc[3] / fmaxf(Ac[3] * s3, 1e-12f), 0.75f, 1.25f);

        asm volatile("" ::: "memory");   // keep passes separate (no fused 64-reg live set)

        float v[NG];
        if (lcls) {
            #pragma unroll
            for (int k = 0; k < 8; ++k) {
                const int ro = 16 * ((k + rot) & 7);
                const float4 a = *(const float4*)(cbase + ro);
                const float4 e = *(const float4*)(cbase + 128 + ro);
                const float4 f = *(const float4*)(cbase + 256 + ro);
                const float4 h = *(const float4*)(cbase + 384 + ro);
                v[4*k+0] = a.x*Ac[0] + e.x*Ac[1] + f.x*Ac[2] + h.x*Ac[3];
                v[4*k+1] = a.y*Ac[0] + e.y*Ac[1] + f.y*Ac[2] + h.y*Ac[3];
                v[4*k+2] = a.z*Ac[0] + e.z*Ac[1] + f.z*Ac[2] + h.z*Ac[3];
                v[4*k+3] = a.w*Ac[0] + e.w*Ac[1] + f.w*Ac[2] + h.w*Ac[3];
            }
        } else if (valid) {
            #pragma unroll
            for (int k = 0; k < 8; ++k) {
                const float4 a = gs[sp_idx(tau, 0, k)];
                const float4 e = gs[sp_idx(tau, 1, k)];
                const float4 f = gs[sp_idx(tau, 2, k)];
                const float4 h = gs[sp_idx(tau, 3, k)];
                v[4*k+0] = a.x*Ac[0] + e.x*Ac[1] + f.x*Ac[2] + h.x*Ac[3];
                v[4*k+1] = a.y*Ac[0] + e.y*Ac[1] + f.y*Ac[2] + h.y*Ac[3];
                v[4*k+2] = a.z*Ac[0] + e.z*Ac[1] + f.z*Ac[2] + h.z*Ac[3];
                v[4*k+3] = a.w*Ac[0] + e.w*Ac[1] + f.w*Ac[2] + h.w*Ac[3];
            }
        } else {
            #pragma unroll
            for (int g = 0; g < NG; ++g) v[g] = 0.f;
        }
        const float tot = wave_sum32(v, lane);
        const int buf = (q & 1) * (8 * NG);
        if (!(lane & 1)) wred[buf + w * NG + g_own] = tot;
        __syncthreads();
        float s = 0.f;
        #pragma unroll
        for (int w2 = 0; w2 < 8; ++w2) s += wred[buf + w2 * NG + g_own];
        Bown *= clampf(Rown / fmaxf(Bown * s, 1e-12f), 0.75f, 1.25f);
    }

    // park A finals in out's g=0 row (positions each k_epi thread reads then
    // overwrites itself) and B finals as 8 replicas at 250-col boundaries in
    // the g=1 row (each k_epi block reads the replica inside its OWN range).
    if (valid) {
        float* ap = out + 1 + (size_t)(b * NG) * ND + c0;
        ap[0] = Ac[0]; ap[1] = Ac[1]; ap[2] = Ac[2]; ap[3] = Ac[3];
    }
    if (w == 0 && !(lane & 1)) {
        #pragma unroll
        for (int qq = 0; qq < 8; ++qq)
            out[1 + (size_t)(b * NG + 1) * ND + qq * 250 + g_own] = Bown;
    }
}

// ---- loss-partials path: 512-thr, r0-verbatim (one (b,cx) pair) ----------
__device__ __forceinline__ void loss_path(
        const float* __restrict__ x, const float* __restrict__ nl,
        const float* __restrict__ tgt, const float* __restrict__ W,
        const float* __restrict__ bias, float* __restrict__ res2,
        float* smem, int cx, int b, int t) {
    float* xsl = smem;                 // 256
    float* nsl = smem + 256;           // 256
    float* tgl = smem + 512;           // 252
    float* pt  = smem + 764;           // 16 x 252

    if (t < 256) {
        const float* xb = x + (size_t)b * NG * NDIN;
        float s = 0.f;
        for (int g = 0; g < NG; ++g) s += xb[g * NDIN + t];
        xsl[t] = s;
        const float* nb = nl + (size_t)b * NG * (NM * NE);
        float s2 = 0.f;
        for (int g = 0; g < NG; ++g) s2 += nb[g * (NM * NE) + t];
        nsl[t] = s2;
    }

    int tm = 0, tn = 0;
    if (t >= 16 && t < 152) {
        int p = t - 16;
        for (int m = 0; m < NM; ++m) {
            int c = NM - m;
            if (p < c) { tm = m; tn = m + p; break; }
            p -= c;
        }
    }
    __syncthreads();

    const int d = cx * 250 + t;
    if (t < 250) {
        tgl[t] = tgt[b * ND + d];
        float xw = 0.f;
        #pragma unroll 8
        for (int k = 0; k < NDIN; ++k) xw += xsl[k] * W[(size_t)k * ND + d];
        float we[NE];
        #pragma unroll
        for (int e = 0; e < NE; ++e) we[e] = W[(size_t)(NDIN + e) * ND + d];
        const float base0 = xw + (float)NG * bias[d];
        #pragma unroll
        for (int m = 0; m < NM; ++m) {
            float pm = base0;
            #pragma unroll
            for (int e = 0; e < NE; ++e) pm += nsl[m * NE + e] * we[e];
            pt[m * 252 + t] = pm;
        }
    }
    if (t < 32) {                      // zero-pad cols 250,251
        pt[(t >> 1) * 252 + 250 + (t & 1)] = 0.f;
        if (t < 2) tgl[250 + t] = 0.f;
    }
    __syncthreads();

    float acc = 0.f;
    if (t < 16) {
        const float4* pa  = (const float4*)&pt[t * 252];
        const float4* tga = (const float4*)&tgl[0];
        for (int i = 0; i < 63; ++i) {
            float4 pv = pa[i], tv = tga[i];
            float e0 = pv.x - tv.x, e1 = pv.y - tv.y, e2 = pv.z - tv.z, e3 = pv.w - tv.w;
            acc += e0 * e0 + e1 * e1 + e2 * e2 + e3 * e3;
        }
    } else if (t < 152) {
        const float4* pa = (const float4*)&pt[tm * 252];
        const float4* pb = (const float4*)&pt[tn * 252];
        for (int i = 0; i < 63; ++i) {
            float4 u = pa[i], v = pb[i];
            acc += u.x * v.x + u.y * v.y + u.z * v.z + u.w * v.w;
        }
    }
    if (t < 152) res2[((size_t)b * 8 + cx) * 152 + t] = acc;
}

extern "C" __global__ __launch_bounds__(512)
void mega(const float* __restrict__ x, const float* __restrict__ nl,
          const float* __restrict__ tgt, const float* __restrict__ W,
          const float* __restrict__ bias, const float* __restrict__ xpT,
          const float* __restrict__ spB, const int* __restrict__ tsum,
          float* __restrict__ out, float* __restrict__ res2) {
    extern __shared__ char smem[];     // 157696 B
    const int bid = blockIdx.x;        // 0..255 (exactly 1 block/CU)
    const int t = threadIdx.x;
    if (bid < NB) {
        ipf_path(xpT, spB, tsum, out, smem, bid, t);
    } else {
        const int l = bid - NB;        // 0..191, grid-stride 512 pairs
        #pragma unroll
        for (int rep = 0; rep < 3; ++rep) {
            const int p = l + rep * 192;
            if (p < 512) {
                __syncthreads();
                loss_path(x, nl, tgt, W, bias, res2, (float*)smem,
                          p & 7, p >> 3, t);
            }
        }
    }
}

// ---------------------------------------------------------------------------
// K_EPI v2: one COLUMN per thread, fully register-resident.
//   c32[32]: col -> z -> frac in-place (static indexing only).
//   yv: packed 4 bytes/dword in 8 VGPRs (values <= 205 < 256).
//   Live set ~55 VGPR -> fits any allocator budget; rank loops are pure
//   VALU reg-reg compares (no LDS scratch, no spill possible).
// Grid (8 chunks, 64 b) x 256 thr (250 active).  Reads A[c] (own col) and
// B replica (own 250-range) from `out`, barrier, then overwrites out.
// ---------------------------------------------------------------------------
extern "C" __global__ __launch_bounds__(256)
void k_epi(const float* __restrict__ xpT, const float* __restrict__ spB,
           const int* __restrict__ tsum, float* __restrict__ out) {
    const int chunk = blockIdx.x;      // 0..7
    const int b     = blockIdx.y;      // 0..63
    const int tt    = threadIdx.x;     // 0..255
    __shared__ float bf[NG];

    if (tt < NG)
        bf[tt] = out[1 + (size_t)(b * NG + 1) * ND + chunk * 250 + tt];
    __syncthreads();
    if (tt >= 250) return;

    const int c = chunk * 250 + tt;
    const float A = out[1 + (size_t)(b * NG) * ND + c];
    const int Ci = tsum[(size_t)b * ND + c];
    const float Cf = (float)Ci;

    // load column into registers (32 floats, static indexing)
    float c32[NG];
    if (c < XPT_COLS) {
        const float4* cp = (const float4*)(xpT + ((size_t)b * XPT_COLS + c) * NG);
        #pragma unroll
        for (int k = 0; k < 8; ++k) {
            const float4 v = cp[k];
            c32[4*k+0] = v.x; c32[4*k+1] = v.y;
            c32[4*k+2] = v.z; c32[4*k+3] = v.w;
        }
    } else {
        const float4* gsp = (const float4*)spB + (size_t)b * SP_STRIDE4;
        const int cc = c - XPT_COLS;
        const int tau2 = cc >> 2, cj = cc & 3;
        #pragma unroll
        for (int k = 0; k < 8; ++k) {
            const float4 v = gsp[sp_idx(tau2, cj, k)];
            c32[4*k+0] = v.x; c32[4*k+1] = v.y;
            c32[4*k+2] = v.z; c32[4*k+3] = v.w;
        }
    }

    // pass 1: z = (y0*A)*B, accumulate s in g-ascending order (r6 FP order)
    float s = 0.f;
    #pragma unroll
    for (int g = 0; g < NG; ++g) {
        const float z = c32[g] * A * bf[g];
        s += z;
        c32[g] = z;
    }
    const float F = Cf / fmaxf(s, 1e-12f);

    // pass 2: floor/frac/yv, isum
    int yvp[8];
    #pragma unroll
    for (int i = 0; i < 8; ++i) yvp[i] = 0;
    int isum = 0;
    #pragma unroll
    for (int g = 0; g < NG; ++g) {
        const float y = c32[g] * F;
        const float fl = floorf(y);
        const int yi = (int)fl;
        c32[g] = y - fl;              // frac, in place
        yadd(yvp, g, yi);
        isum += yi;
    }
    const int need = Ci - isum;
    const int pos = max(need, 0);
    const int qv = pos >> 5;
    const int rr = pos & 31;
    if (qv > 0) {
        #pragma unroll
        for (int i = 0; i < 8; ++i) yvp[i] += qv * 0x01010101;
    }
    #pragma unroll
    for (int g = 0; g < NG; ++g) {     // stable DESCENDING rank on frac
        const float fg = c32[g];
        int rank = 0;
        #pragma unroll
        for (int h = 0; h < NG; ++h) {
            if (h == g) continue;
            const float fh = c32[h];
            rank += (h < g) ? (fh >= fg ? 1 : 0) : (fh > fg ? 1 : 0);
        }
        if (rank < rr) yadd(yvp, g, 1);
    }
    // negative residual: one-shot ascending rank among yv>0 (== reference)
    int neg = max(-need, 0);
    neg = min(neg, isum);
    if (__builtin_expect(neg > 0, 0)) {
        const int q2 = neg >> 5;
        int removed = 0;
        #pragma unroll
        for (int g = 0; g < NG; ++g) {
            const int yb = yget(yvp, g);
            const int yn = max(yb - q2, 0);
            removed += yb - yn;
            yadd(yvp, g, yn - yb);
        }
        const int r2 = neg - removed;
        if (r2 > 0) {
            const float INF = __builtin_inff();
            #pragma unroll
            for (int g = 0; g < NG; ++g) {
                const float fg = (yget(yvp, g) > 0) ? c32[g] : INF;
                int rank = 0;
                #pragma unroll
                for (int h = 0; h < NG; ++h) {
                    if (h == g) continue;
                    const float fh = (yget(yvp, h) > 0) ? c32[h] : INF;
                    rank += (h < g) ? (fh <= fg ? 1 : 0) : (fh < fg ? 1 : 0);
                }
                if (rank < r2) {
                    const int yb = yget(yvp, g);
                    yadd(yvp, g, max(yb - 1, 0) - yb);
                }
            }
        }
    }
    #pragma unroll
    for (int g = 0; g < NG; ++g)
        out[1 + (size_t)(b * NG + g) * ND + c] = (float)yget(yvp, g);
}

// K2b: combine the 8 d-chunk partials per b and accumulate the loss.
extern "C" __global__ __launch_bounds__(64)
void k2b_combine(const float* __restrict__ res2, float* __restrict__ out) {
    const int b = blockIdx.x, t = threadIdx.x;
    __shared__ float res[152];
    for (int tau = t; tau < 152; tau += 64) {
        float s = 0.f;
        #pragma unroll
        for (int c = 0; c < 8; ++c) s += res2[((size_t)b * 8 + c) * 152 + tau];
        res[tau] = s;
    }
    __syncthreads();
    if (t == 0) {
        float conf = 0.f;
        for (int m = 0; m < NM; ++m) conf += sqrtf(res[m]);
        conf *= (1.f / NM);
        float pd = 0.f;
        for (int m = 0; m < NM; ++m) {
            const int offm = 16 + m * NM - m * (m - 1) / 2;
            const float sqm = res[offm];
            for (int n = m + 1; n < NM; ++n) {
                const int offn = 16 + n * NM - n * (n - 1) / 2;
                const float sqn = res[offn];
                const float inn = res[offm + (n - m)];
                pd += sqrtf(fmaxf(sqm + sqn - 2.f * inn, 1e-6f));
            }
        }
        pd = 2.f * pd / (float)(NM * (NM - 1));
        atomicAdd(out, (conf - 0.5f * pd) * (1.f / NB));
    }
}

// ---------------------------------------------------------------------------
// K3: x_pred = softplus(concat(x, noise_sample) @ W + bias); cols < 1216 to
// xpT [b][c][g], cols >= 1216 to the lane-interleaved streamP layout.
// ---------------------------------------------------------------------------
extern "C" __global__ __launch_bounds__(256)
void k3_xpred(const float* __restrict__ x, const float* __restrict__ nsamp,
              const float* __restrict__ W, const float* __restrict__ bias,
              float* __restrict__ xpT, float* __restrict__ spB) {
    const int dx = blockIdx.x;     // 0..1
    const int rb = blockIdx.y;     // 0..255
    const int t  = threadIdx.x;
    __shared__ float xr[8][NK];
    #pragma unroll
    for (int r = 0; r < 8; ++r) {
        const int row = rb * 8 + r;
        xr[r][t] = x[(size_t)row * NDIN + t];
        if (t < NE) xr[r][NDIN + t] = nsamp[row * NE + t];
    }
    __syncthreads();
    if (t >= 250) return;
    const int d = dx * 1000 + 4 * t;
    float acc[8][4];
    #pragma unroll
    for (int r = 0; r < 8; ++r) {
        acc[r][0] = 0.f; acc[r][1] = 0.f; acc[r][2] = 0.f; acc[r][3] = 0.f;
    }
    for (int k = 0; k < NK; k += 4) {
        float4 w[4];
        #pragma unroll
        for (int kk = 0; kk < 4; ++kk) w[kk] = *(const float4*)&W[(size_t)(k + kk) * ND + d];
        #pragma unroll
        for (int r = 0; r < 8; ++r) {
            const float4 xv = *(const float4*)&xr[r][k];
            acc[r][0] += xv.x * w[0].x + xv.y * w[1].x + xv.z * w[2].x + xv.w * w[3].x;
            acc[r][1] += xv.x * w[0].y + xv.y * w[1].y + xv.z * w[2].y + xv.w * w[3].y;
            acc[r][2] += xv.x * w[0].z + xv.y * w[1].z + xv.z * w[2].z + xv.w * w[3].z;
            acc[r][3] += xv.x * w[0].w + xv.y * w[1].w + xv.z * w[2].w + xv.w * w[3].w;
        }
    }
    const float4 bv = *(const float4*)&bias[d];
    const float bvv[4] = {bv.x, bv.y, bv.z, bv.w};
    const int b2 = rb >> 2;            // b = row/32
    const int g0 = (rb & 3) * 8;       // this block's 8-g slice
    #pragma unroll
    for (int dd = 0; dd < 4; ++dd) {
        const int dc = d + dd;
        float4 lo, hi;
        lo.x = softplusf(acc[0][dd] + bvv[dd]);
        lo.y = softplusf(acc[1][dd] + bvv[dd]);
        lo.z = softplusf(acc[2][dd] + bvv[dd]);
        lo.w = softplusf(acc[3][dd] + bvv[dd]);
        hi.x = softplusf(acc[4][dd] + bvv[dd]);
        hi.y = softplusf(acc[5][dd] + bvv[dd]);
        hi.z = softplusf(acc[6][dd] + bvv[dd]);
        hi.w = softplusf(acc[7][dd] + bvv[dd]);
        if (dc < XPT_COLS) {
            float* op = xpT + ((size_t)b2 * XPT_COLS + dc) * NG + g0;
            *(float4*)op       = lo;
            *(float4*)(op + 4) = hi;
        } else {
            float4* sp = (float4*)spB + (size_t)b2 * SP_STRIDE4;
            const int cc = dc - XPT_COLS;
            const int tau2 = cc >> 2, cj = cc & 3;
            const int kk = g0 >> 2;
            sp[sp_idx(tau2, cj, kk)]     = lo;
            sp[sp_idx(tau2, cj, kk + 1)] = hi;
        }
    }
}

// ---------------------------------------------------------------------------
extern "C" void kernel_launch(void* const* d_in, const int* in_sizes, int n_in,
                              void* d_out, int out_size, void* d_ws, size_t ws_size,
                              hipStream_t stream) {
    const float* x     = (const float*)d_in[0];
    const float* tgt   = (const float*)d_in[1];
    const int*   tsum  = (const int*)d_in[2];
    const float* W     = (const float*)d_in[3];
    const float* bias  = (const float*)d_in[4];
    const float* nl    = (const float*)d_in[5];
    const float* nsamp = (const float*)d_in[6];
    float* out = (float*)d_out;

    (void)in_sizes; (void)n_in; (void)out_size; (void)ws_size;

    // ws layout (total 16,695,296 B == proven footprint):
    //   xpT:     64 * 1216 cols * 32 g * 4 B      =  9,961,472
    //   streamP: 64 * 6272 float4 * 16 B          =  6,422,528
    //   res2:    64 * 8 * 152 * 4 B               =    311,296
    float* xpT  = (float*)d_ws;
    float* spB  = (float*)((char*)d_ws + 9961472);
    float* res2 = (float*)((char*)d_ws + 16384000);

    static int s_attr_done = 0;
    if (!s_attr_done) {
        hipFuncSetAttribute(reinterpret_cast<const void*>(mega),
                            hipFuncAttributeMaxDynamicSharedMemorySize,
                            SMEM_MEGA);
        s_attr_done = 1;
    }

    hipMemsetAsync(d_out, 0, sizeof(float), stream);   // loss accumulator

    hipLaunchKernelGGL(k3_xpred, dim3(2, 256), dim3(256), 0, stream,
                       x, nsamp, W, bias, xpT, spB);
    hipLaunchKernelGGL(mega, dim3(256), dim3(512), SMEM_MEGA, stream,
                       x, nl, tgt, W, bias, xpT, spB, tsum, out, res2);
    hipLaunchKernelGGL(k_epi, dim3(8, 64), dim3(256), 0, stream,
                       xpT, spB, tsum, out);
    hipLaunchKernelGGL(k2b_combine, dim3(NB), dim3(64), 0, stream, res2, out);
}

// Round 9
// 364.166 us; speedup vs baseline: 1.2221x; 1.2221x over previous
//
#include <hip/hip_runtime.h>
#include <math.h>

// Problem constants (match reference)
#define NB   64     // num_groups (B)
#define NG   32     // group_size (G)
#define ND   2000   // output dim D
#define NM   16     // m_samples
#define NE   16     // noise dim
#define NDIN 256
#define NK   272    // DIN + E

// ---------------------------------------------------------------------------
// Round-8 design, from 7 rounds of profile evidence:
//  - r7 regression root-caused: LDS/stream split at 304 thr = 4.75 waves ->
//    split wave serializes both paths, barrier waits on it (+0.9us/iter).
//    Splits MUST be wave-aligned.
//  - r1's SPILLED mega was 181us (3us/iter) with 16 waves streaming L2;
//    r6's clean 8-wave version is 4us/iter.  Floors (LDS 0.85, stream 1.6)
//    sum << 4us -> loop is LATENCY-bound; the lever is 16 waves, not BW.
//  - So: 1024-thr IPF blocks (16 waves, r1/r2 FP structure, passed), 2
//    cols/thread, no-spill two-pass loop (r3-r7).  Wave-aligned split:
//    t<576 (9 waves) own 1152 LDS cols (151.5KB, r3 proved this size
//    launches); t 576..999 stream 848 cols via packed coalesced layout.
//  - Epilogue INLINED (r7 k_epi register code: c32[32]+packed yvp[8] ~50
//    live regs < 64-reg floor) -> kills k_epi kernel + 16MB re-read +
//    A/B parking.  memset folded into k3 -> 3 graph nodes (was 5).
// ---------------------------------------------------------------------------
#define XPT_COLS 1152                       // cols 0..1151 LDS-class
#define SP_TAU   424                        // stream threads (848 cols / 2)
#define SP_F4_PER_B 6784                    // 2*8*424 float4 per b
#define SMEM_MEGA (4096 + XPT_COLS * 128)   // 4KB wred + 147KB cols = 151552

__device__ __forceinline__ float clampf(float v, float lo, float hi) {
    return fminf(fmaxf(v, lo), hi);
}

__device__ __forceinline__ float softplusf(float v) {
    return (v > 20.f) ? v : log1pf(expf(v));
}

__device__ __forceinline__ float readlane_f(float v, int lane) {
    return __int_as_float(__builtin_amdgcn_readlane(__float_as_int(v), lane));
}

// streamP float4 index within one b: [j(col parity)][k(g-quad)][tau].
// For fixed (j,k) a wave's 64 lanes read 64 consecutive float4 = coalesced.
__device__ __forceinline__ int sp_idx(int tau, int j, int k) {
    return (j * 8 + k) * SP_TAU + tau;
}

// packed-byte yv helpers (g compile-time constant after unroll; yv<=205<256)
__device__ __forceinline__ int yget(const int* yvp, int g) {
    return (yvp[g >> 2] >> (8 * (g & 3))) & 0xff;
}
__device__ __forceinline__ void yadd(int* yvp, int g, int delta) {
    yvp[g >> 2] += delta << (8 * (g & 3));
}

// Fully-packed butterfly: reduce v[0..31] (per-g partials) across 64 lanes in
// 32 shuffles.  Returns the wave total for g = (lane>>1)&31 (dup on pairs).
__device__ __forceinline__ float wave_sum32(float v[NG], int lane) {
    {   const bool hi = (lane & 32) != 0;
        #pragma unroll
        for (int k = 0; k < 16; ++k) {
            float s = hi ? v[k] : v[k + 16];
            float r = __shfl_xor(s, 32);
            v[k] = (hi ? v[k + 16] : v[k]) + r;
        }
    }
    {   const bool hi = (lane & 16) != 0;
        #pragma unroll
        for (int k = 0; k < 8; ++k) {
            float s = hi ? v[k] : v[k + 8];
            float r = __shfl_xor(s, 16);
            v[k] = (hi ? v[k + 8] : v[k]) + r;
        }
    }
    {   const bool hi = (lane & 8) != 0;
        #pragma unroll
        for (int k = 0; k < 4; ++k) {
            float s = hi ? v[k] : v[k + 4];
            float r = __shfl_xor(s, 8);
            v[k] = (hi ? v[k + 4] : v[k]) + r;
        }
    }
    {   const bool hi = (lane & 4) != 0;
        #pragma unroll
        for (int k = 0; k < 2; ++k) {
            float s = hi ? v[k] : v[k + 2];
            float r = __shfl_xor(s, 4);
            v[k] = (hi ? v[k + 2] : v[k]) + r;
        }
    }
    {   const bool hi = (lane & 2) != 0;
        float s = hi ? v[0] : v[1];
        float r = __shfl_xor(s, 2);
        v[0] = (hi ? v[1] : v[0]) + r;
    }
    v[0] += __shfl_xor(v[0], 1);
    return v[0];
}

// ---- IPF path: 1024 thr (16 waves), thread owns cols c0, c0+1 ------------
__device__ __forceinline__ void ipf_path(
        const float* __restrict__ xpT, const float* __restrict__ spB,
        const int* __restrict__ tsum, float* __restrict__ out,
        char* smem, int b, int t) {
    const int lane = t & 63, w = t >> 6;       // 16 waves
    const bool lcls  = (t < 576);              // 9 waves: cols in LDS
    const bool valid = (t < 1000);
    const int g_own = (lane >> 1) & 31;
    const int rot = t & 7;
    const int tau = t - 576;                   // stream thread index
    const int c0 = lcls ? (2 * t) : (XPT_COLS + 2 * tau);

    float* wred = (float*)smem;                // [2][16][32] dbuf
    char* cb = smem + 4096 + (size_t)c0 * 128; // col c0 base; c0+1 at +128
    const float4* gx = (const float4*)(xpT + ((size_t)b * XPT_COLS + c0) * NG);
    const float4* gs = (const float4*)spB + (size_t)b * SP_F4_PER_B;

    float Cc0 = 0.f, Cc1 = 0.f;
    if (valid) {
        const int2 ci = *(const int2*)(tsum + (size_t)b * ND + c0);
        Cc0 = (float)ci.x; Cc1 = (float)ci.y;
    }
    float Ac0 = 1.f, Ac1 = 1.f;
    float Bown = 1.f, Rown;

    // prologue: load 2 cols, stash LDS-class (16B chunks rotated by
    // (k+rot)&7: lane quad = (k+lane)&7 -> 2 lanes/bank = conflict-free),
    // compute row anchors R (16-wave combine, r2 FP order).
    {
        float v[NG];
        if (lcls) {
            #pragma unroll
            for (int k = 0; k < 8; ++k) {
                const float4 a = gx[k], c = gx[8 + k];
                const int ro = 16 * ((k + rot) & 7);
                *(float4*)(cb + ro)       = a;
                *(float4*)(cb + 128 + ro) = c;
                v[4*k+0] = a.x + c.x;
                v[4*k+1] = a.y + c.y;
                v[4*k+2] = a.z + c.z;
                v[4*k+3] = a.w + c.w;
            }
        } else if (valid) {
            #pragma unroll
            for (int k = 0; k < 8; ++k) {
                const float4 a = gs[sp_idx(tau, 0, k)];
                const float4 c = gs[sp_idx(tau, 1, k)];
                v[4*k+0] = a.x + c.x;
                v[4*k+1] = a.y + c.y;
                v[4*k+2] = a.z + c.z;
                v[4*k+3] = a.w + c.w;
            }
        } else {
            #pragma unroll
            for (int g = 0; g < NG; ++g) v[g] = 0.f;
        }
        const float tot = wave_sum32(v, lane);
        if (!(lane & 1)) wred[w * NG + g_own] = tot;
        __syncthreads();
        float s = 0.f;
        #pragma unroll
        for (int w2 = 0; w2 < 16; ++w2) s += wred[w2 * NG + g_own];
        Rown = s;
    }

    // 60 IPF iterations, one barrier each (dbuf wred)
    for (int q = 1; q <= 60; ++q) {
        // ---- column pass: s(c) = sum_g y0[g,c] * B[g] ----
        float s0 = 0.f, s1 = 0.f;
        if (lcls) {
            #pragma unroll
            for (int k = 0; k < 8; ++k) {
                const int ro = 16 * ((k + rot) & 7);
                const float4 a = *(const float4*)(cb + ro);
                const float4 c = *(const float4*)(cb + 128 + ro);
                float bg;
                bg = readlane_f(Bown, 8*k+0); s0 += a.x*bg; s1 += c.x*bg;
                bg = readlane_f(Bown, 8*k+2); s0 += a.y*bg; s1 += c.y*bg;
                bg = readlane_f(Bown, 8*k+4); s0 += a.z*bg; s1 += c.z*bg;
                bg = readlane_f(Bown, 8*k+6); s0 += a.w*bg; s1 += c.w*bg;
            }
        } else if (valid) {
            #pragma unroll
            for (int k = 0; k < 8; ++k) {
                const float4 a = gs[sp_idx(tau, 0, k)];
                const float4 c = gs[sp_idx(tau, 1, k)];
                float bg;
                bg = readlane_f(Bown, 8*k+0); s0 += a.x*bg; s1 += c.x*bg;
                bg = readlane_f(Bown, 8*k+2); s0 += a.y*bg; s1 += c.y*bg;
                bg = readlane_f(Bown, 8*k+4); s0 += a.z*bg; s1 += c.z*bg;
                bg = readlane_f(Bown, 8*k+6); s0 += a.w*bg; s1 += c.w*bg;
            }
        }
        Ac0 *= clampf(Cc0 / fmaxf(Ac0 * s0, 1e-12f), 0.75f, 1.25f);
        Ac1 *= clampf(Cc1 / fmaxf(Ac1 * s1, 1e-12f), 0.75f, 1.25f);

        asm volatile("" ::: "memory");   // keep passes separate (reg pressure)

        // ---- row pass: v[g] = y0[g,c0]*A[c0] + y0[g,c1]*A[c1] ----
        float v[NG];
        if (lcls) {
            #pragma unroll
            for (int k = 0; k < 8; ++k) {
                const int ro = 16 * ((k + rot) & 7);
                const float4 a = *(const float4*)(cb + ro);
                const float4 c = *(const float4*)(cb + 128 + ro);
                v[4*k+0] = a.x * Ac0 + c.x * Ac1;
                v[4*k+1] = a.y * Ac0 + c.y * Ac1;
                v[4*k+2] = a.z * Ac0 + c.z * Ac1;
                v[4*k+3] = a.w * Ac0 + c.w * Ac1;
            }
        } else if (valid) {
            #pragma unroll
            for (int k = 0; k < 8; ++k) {
                const float4 a = gs[sp_idx(tau, 0, k)];
                const float4 c = gs[sp_idx(tau, 1, k)];
                v[4*k+0] = a.x * Ac0 + c.x * Ac1;
                v[4*k+1] = a.y * Ac0 + c.y * Ac1;
                v[4*k+2] = a.z * Ac0 + c.z * Ac1;
                v[4*k+3] = a.w * Ac0 + c.w * Ac1;
            }
        } else {
            #pragma unroll
            for (int g = 0; g < NG; ++g) v[g] = 0.f;
        }
        const float tot = wave_sum32(v, lane);
        const int buf = (q & 1) * (16 * NG);
        if (!(lane & 1)) wred[buf + w * NG + g_own] = tot;
        __syncthreads();
        float s = 0.f;
        #pragma unroll
        for (int w2 = 0; w2 < 16; ++w2) s += wred[buf + w2 * NG + g_own];
        Bown *= clampf(Rown / fmaxf(Bown * s, 1e-12f), 0.75f, 1.25f);
    }

    // ---- epilogue INLINE (r7 k_epi register code; ~50 live regs) ----
    if (!valid) return;

    #pragma unroll
    for (int jj = 0; jj < 2; ++jj) {
        const int c = c0 + jj;
        const float A = jj ? Ac1 : Ac0;
        const int Ci = (int)(jj ? Cc1 : Cc0);
        const float Cf = (float)Ci;

        // load column into registers (static indexing)
        float c32[NG];
        if (lcls) {
            const char* basej = cb + jj * 128;
            #pragma unroll
            for (int k = 0; k < 8; ++k) {
                const float4 v4 = *(const float4*)(basej + 16 * ((k + rot) & 7));
                c32[4*k+0] = v4.x; c32[4*k+1] = v4.y;
                c32[4*k+2] = v4.z; c32[4*k+3] = v4.w;
            }
        } else {
            #pragma unroll
            for (int k = 0; k < 8; ++k) {
                const float4 v4 = gs[sp_idx(tau, jj, k)];
                c32[4*k+0] = v4.x; c32[4*k+1] = v4.y;
                c32[4*k+2] = v4.z; c32[4*k+3] = v4.w;
            }
        }

        // pass 1: z = (y0*A)*B, accumulate s (g ascending, proven FP order)
        float s = 0.f;
        #pragma unroll
        for (int g = 0; g < NG; ++g) {
            const float z = c32[g] * A * readlane_f(Bown, 2 * g);
            s += z;
            c32[g] = z;
        }
        const float F = Cf / fmaxf(s, 1e-12f);

        // pass 2: floor/frac/yv (packed), isum
        int yvp[8];
        #pragma unroll
        for (int i = 0; i < 8; ++i) yvp[i] = 0;
        int isum = 0;
        #pragma unroll
        for (int g = 0; g < NG; ++g) {
            const float y = c32[g] * F;
            const float fl = floorf(y);
            const int yi = (int)fl;
            c32[g] = y - fl;              // frac, in place
            yadd(yvp, g, yi);
            isum += yi;
        }
        const int need = Ci - isum;
        const int pos = max(need, 0);
        const int qv = pos >> 5;
        const int rr = pos & 31;
        if (qv > 0) {
            #pragma unroll
            for (int i = 0; i < 8; ++i) yvp[i] += qv * 0x01010101;
        }
        #pragma unroll
        for (int g = 0; g < NG; ++g) {     // stable DESCENDING rank on frac
            const float fg = c32[g];
            int rank = 0;
            #pragma unroll
            for (int h = 0; h < NG; ++h) {
                if (h == g) continue;
                const float fh = c32[h];
                rank += (h < g) ? (fh >= fg ? 1 : 0) : (fh > fg ? 1 : 0);
            }
            if (rank < rr) yadd(yvp, g, 1);
        }
        // negative residual: one-shot ascending rank among yv>0 (==reference)
        int neg = max(-need, 0);
        neg = min(neg, isum);
        if (__builtin_expect(neg > 0, 0)) {
            const int q2 = neg >> 5;
            int removed = 0;
            #pragma unroll
            for (int g = 0; g < NG; ++g) {
                const int yb = yget(yvp, g);
                const int yn = max(yb - q2, 0);
                removed += yb - yn;
                yadd(yvp, g, yn - yb);
            }
            const int r2 = neg - removed;
            if (r2 > 0) {
                const float INF = __builtin_inff();
                #pragma unroll
                for (int g = 0; g < NG; ++g) {
                    const float fg = (yget(yvp, g) > 0) ? c32[g] : INF;
                    int rank = 0;
                    #pragma unroll
                    for (int h = 0; h < NG; ++h) {
                        if (h == g) continue;
                        const float fh = (yget(yvp, h) > 0) ? c32[h] : INF;
                        rank += (h < g) ? (fh <= fg ? 1 : 0) : (fh < fg ? 1 : 0);
                    }
                    if (rank < r2) {
                        const int yb = yget(yvp, g);
                        yadd(yvp, g, max(yb - 1, 0) - yb);
                    }
                }
            }
        }
        #pragma unroll
        for (int g = 0; g < NG; ++g)
            out[1 + (size_t)(b * NG + g) * ND + c] = (float)yget(yvp, g);
    }
}

// ---- loss-partials path: 1024 thr = two 512-halves (r2-verbatim) ---------
__device__ __forceinline__ void loss_path(
        const float* __restrict__ x, const float* __restrict__ nl,
        const float* __restrict__ tgt, const float* __restrict__ W,
        const float* __restrict__ bias, float* __restrict__ res2,
        float* smem, int cx, int b, int tt) {
    const int half = cx & 1;
    float* xsl = smem;                         // 256 (shared across halves)
    float* nsl = smem + 256;                   // 256 (shared across halves)
    float* tgl = smem + 512 + half * 4284;     // 252 per half
    float* pt  = tgl + 252;                    // 16 x 252 per half

    if (half == 0 && tt < 256) {               // == global t < 256
        const float* xb = x + (size_t)b * NG * NDIN;
        float s = 0.f;
        for (int g = 0; g < NG; ++g) s += xb[g * NDIN + tt];
        xsl[tt] = s;
        const float* nb = nl + (size_t)b * NG * (NM * NE);
        float s2 = 0.f;
        for (int g = 0; g < NG; ++g) s2 += nb[g * (NM * NE) + tt];
        nsl[tt] = s2;
    }

    int tm = 0, tn = 0;
    if (tt >= 16 && tt < 152) {
        int p = tt - 16;
        for (int m = 0; m < NM; ++m) {
            int c = NM - m;
            if (p < c) { tm = m; tn = m + p; break; }
            p -= c;
        }
    }
    __syncthreads();

    const int d = cx * 250 + tt;
    if (tt < 250) {
        tgl[tt] = tgt[b * ND + d];
        float xw = 0.f;
        #pragma unroll 8
        for (int k = 0; k < NDIN; ++k) xw += xsl[k] * W[(size_t)k * ND + d];
        float we[NE];
        #pragma unroll
        for (int e = 0; e < NE; ++e) we[e] = W[(size_t)(NDIN + e) * ND + d];
        const float base0 = xw + (float)NG * bias[d];
        #pragma unroll
        for (int m = 0; m < NM; ++m) {
            float pm = base0;
            #pragma unroll
            for (int e = 0; e < NE; ++e) pm += nsl[m * NE + e] * we[e];
            pt[m * 252 + tt] = pm;
        }
    }
    if (tt < 32) {                     // zero-pad cols 250,251
        pt[(tt >> 1) * 252 + 250 + (tt & 1)] = 0.f;
        if (tt < 2) tgl[250 + tt] = 0.f;
    }
    __syncthreads();

    float acc = 0.f;
    if (tt < 16) {
        const float4* pa  = (const float4*)&pt[tt * 252];
        const float4* tga = (const float4*)&tgl[0];
        for (int i = 0; i < 63; ++i) {
            float4 pv = pa[i], tv = tga[i];
            float e0 = pv.x - tv.x, e1 = pv.y - tv.y, e2 = pv.z - tv.z, e3 = pv.w - tv.w;
            acc += e0 * e0 + e1 * e1 + e2 * e2 + e3 * e3;
        }
    } else if (tt < 152) {
        const float4* pa = (const float4*)&pt[tm * 252];
        const float4* pb = (const float4*)&pt[tn * 252];
        for (int i = 0; i < 63; ++i) {
            float4 u = pa[i], v = pb[i];
            acc += u.x * v.x + u.y * v.y + u.z * v.z + u.w * v.w;
        }
    }
    if (tt < 152) res2[((size_t)b * 8 + cx) * 152 + tt] = acc;
}

extern "C" __global__ __launch_bounds__(1024)
void mega(const float* __restrict__ x, const float* __restrict__ nl,
          const float* __restrict__ tgt, const float* __restrict__ W,
          const float* __restrict__ bias, const float* __restrict__ xpT,
          const float* __restrict__ spB, const int* __restrict__ tsum,
          float* __restrict__ out, float* __restrict__ res2) {
    extern __shared__ char smem[];     // 151552 B
    const int bid = blockIdx.x;        // 0..255 (1 block/CU)
    const int t = threadIdx.x;
    if (bid < NB) {
        ipf_path(xpT, spB, tsum, out, smem, bid, t);
    } else {
        const int l = bid - NB;        // 0..191; 256 slots, 2 halves each
        #pragma unroll
        for (int rep = 0; rep < 2; ++rep) {
            const int slot = l + rep * 192;
            if (slot < 256) {
                __syncthreads();
                const int cx = ((slot & 3) << 1) | (t >> 9);
                loss_path(x, nl, tgt, W, bias, res2, (float*)smem,
                          cx, slot >> 2, t & 511);
            }
        }
    }
}

// K2b: combine the 8 d-chunk partials per b and accumulate the loss.
extern "C" __global__ __launch_bounds__(64)
void k2b_combine(const float* __restrict__ res2, float* __restrict__ out) {
    const int b = blockIdx.x, t = threadIdx.x;
    __shared__ float res[152];
    for (int tau = t; tau < 152; tau += 64) {
        float s = 0.f;
        #pragma unroll
        for (int c = 0; c < 8; ++c) s += res2[((size_t)b * 8 + c) * 152 + tau];
        res[tau] = s;
    }
    __syncthreads();
    if (t == 0) {
        float conf = 0.f;
        for (int m = 0; m < NM; ++m) conf += sqrtf(res[m]);
        conf *= (1.f / NM);
        float pd = 0.f;
        for (int m = 0; m < NM; ++m) {
            const int offm = 16 + m * NM - m * (m - 1) / 2;
            const float sqm = res[offm];
            for (int n = m + 1; n < NM; ++n) {
                const int offn = 16 + n * NM - n * (n - 1) / 2;
                const float sqn = res[offn];
                const float inn = res[offm + (n - m)];
                pd += sqrtf(fmaxf(sqm + sqn - 2.f * inn, 1e-6f));
            }
        }
        pd = 2.f * pd / (float)(NM * (NM - 1));
        atomicAdd(out, (conf - 0.5f * pd) * (1.f / NB));
    }
}

// ---------------------------------------------------------------------------
// K3: x_pred = softplus(concat(x, noise_sample) @ W + bias); cols < 1152 to
// xpT [b][c][g], cols >= 1152 to the coalesced streamP layout.  Also zeroes
// out[0] (loss accumulator) - replaces the memset node.
// ---------------------------------------------------------------------------
extern "C" __global__ __launch_bounds__(256)
void k3_xpred(const float* __restrict__ x, const float* __restrict__ nsamp,
              const float* __restrict__ W, const float* __restrict__ bias,
              float* __restrict__ xpT, float* __restrict__ spB,
              float* __restrict__ out) {
    const int dx = blockIdx.x;     // 0..1
    const int rb = blockIdx.y;     // 0..255
    const int t  = threadIdx.x;
    if (dx == 0 && rb == 0 && t == 0) out[0] = 0.f;   // loss accumulator init
    __shared__ float xr[8][NK];
    #pragma unroll
    for (int r = 0; r < 8; ++r) {
        const int row = rb * 8 + r;
        xr[r][t] = x[(size_t)row * NDIN + t];
        if (t < NE) xr[r][NDIN + t] = nsamp[row * NE + t];
    }
    __syncthreads();
    if (t >= 250) return;
    const int d = dx * 1000 + 4 * t;
    float acc[8][4];
    #pragma unroll
    for (int r = 0; r < 8; ++r) {
        acc[r][0] = 0.f; acc[r][1] = 0.f; acc[r][2] = 0.f; acc[r][3] = 0.f;
    }
    for (int k = 0; k < NK; k += 4) {
        float4 w[4];
        #pragma unroll
        for (int kk = 0; kk < 4; ++kk) w[kk] = *(const float4*)&W[(size_t)(k + kk) * ND + d];
        #pragma unroll
        for (int r = 0; r < 8; ++r) {
            const float4 xv = *(const float4*)&xr[r][k];
            acc[r][0] += xv.x * w[0].x + xv.y * w[1].x + xv.z * w[2].x + xv.w * w[3].x;
            acc[r][1] += xv.x * w[0].y + xv.y * w[1].y + xv.z * w[2].y + xv.w * w[3].y;
            acc[r][2] += xv.x * w[0].z + xv.y * w[1].z + xv.z * w[2].z + xv.w * w[3].z;
            acc[r][3] += xv.x * w[0].w + xv.y * w[1].w + xv.z * w[2].w + xv.w * w[3].w;
        }
    }
    const float4 bv = *(const float4*)&bias[d];
    const float bvv[4] = {bv.x, bv.y, bv.z, bv.w};
    const int b2 = rb >> 2;            // b = row/32
    const int g0 = (rb & 3) * 8;       // this block's 8-g slice
    #pragma unroll
    for (int dd = 0; dd < 4; ++dd) {
        const int dc = d + dd;
        float4 lo, hi;
        lo.x = softplusf(acc[0][dd] + bvv[dd]);
        lo.y = softplusf(acc[1][dd] + bvv[dd]);
        lo.z = softplusf(acc[2][dd] + bvv[dd]);
        lo.w = softplusf(acc[3][dd] + bvv[dd]);
        hi.x = softplusf(acc[4][dd] + bvv[dd]);
        hi.y = softplusf(acc[5][dd] + bvv[dd]);
        hi.z = softplusf(acc[6][dd] + bvv[dd]);
        hi.w = softplusf(acc[7][dd] + bvv[dd]);
        if (dc < XPT_COLS) {
            float* op = xpT + ((size_t)b2 * XPT_COLS + dc) * NG + g0;
            *(float4*)op       = lo;
            *(float4*)(op + 4) = hi;
        } else {
            float4* sp = (float4*)spB + (size_t)b2 * SP_F4_PER_B;
            const int cc = dc - XPT_COLS;
            const int tau2 = cc >> 1, j = cc & 1;
            const int kk = g0 >> 2;
            sp[sp_idx(tau2, j, kk)]     = lo;
            sp[sp_idx(tau2, j, kk + 1)] = hi;
        }
    }
}

// ---------------------------------------------------------------------------
extern "C" void kernel_launch(void* const* d_in, const int* in_sizes, int n_in,
                              void* d_out, int out_size, void* d_ws, size_t ws_size,
                              hipStream_t stream) {
    const float* x     = (const float*)d_in[0];
    const float* tgt   = (const float*)d_in[1];
    const int*   tsum  = (const int*)d_in[2];
    const float* W     = (const float*)d_in[3];
    const float* bias  = (const float*)d_in[4];
    const float* nl    = (const float*)d_in[5];
    const float* nsamp = (const float*)d_in[6];
    float* out = (float*)d_out;

    (void)in_sizes; (void)n_in; (void)out_size; (void)ws_size;

    // ws layout (total 16,695,296 B == proven footprint):
    //   xpT:     64 * 1152 cols * 32 g * 4 B  =  9,437,184
    //   streamP: 64 * 6784 float4 * 16 B      =  6,946,816   (sum 16,384,000)
    //   res2:    64 * 8 * 152 * 4 B           =    311,296
    float* xpT  = (float*)d_ws;
    float* spB  = (float*)((char*)d_ws + 9437184);
    float* res2 = (float*)((char*)d_ws + 16384000);

    static int s_attr_done = 0;
    if (!s_attr_done) {
        hipFuncSetAttribute(reinterpret_cast<const void*>(mega),
                            hipFuncAttributeMaxDynamicSharedMemorySize,
                            SMEM_MEGA);
        s_attr_done = 1;
    }

    hipLaunchKernelGGL(k3_xpred, dim3(2, 256), dim3(256), 0, stream,
                       x, nsamp, W, bias, xpT, spB, out);
    hipLaunchKernelGGL(mega, dim3(256), dim3(1024), SMEM_MEGA, stream,
                       x, nl, tgt, W, bias, xpT, spB, tsum, out, res2);
    hipLaunchKernelGGL(k2b_combine, dim3(NB), dim3(64), 0, stream, res2, out);
}

// Round 10
// 344.594 us; speedup vs baseline: 1.2916x; 1.0568x over previous
//
#include <hip/hip_runtime.h>
#include <math.h>

// Problem constants (match reference)
#define NB   64     // num_groups (B)
#define NG   32     // group_size (G)
#define ND   2000   // output dim D
#define NM   16     // m_samples
#define NE   16     // noise dim
#define NDIN 256
#define NK   272    // DIN + E

// ---------------------------------------------------------------------------
// Round-10, from r9 profile:
//  - r9 mega WRITE 67MB (+50MB over legit) = the INLINED epilogue spilled
//    (c32[32]+yvp[8] on top of loop state > the 64-VGPR cap 1024-thr blocks
//    force).  Typical mega 235us => loop alone ~2.7us/iter: the 16-wave
//    latency-hiding DID work (r6 8-wave loop was 4us/iter).
//  - Fix: mega keeps the r9 16-wave loop, epilogue moves back OUT to the
//    r7-proven register-resident k_epi (standalone 256-thr kernel, ~50 live
//    regs, spill-free, sub-top-5 fast).  A/B handoff via r7's proven
//    parking: A finals in out g=0 row (same-thread read-then-overwrite),
//    B finals as 8 replicas at 250-col boundaries in g=1 row (read by the
//    owning block before any of its writes; barrier after load).
// ---------------------------------------------------------------------------
#define XPT_COLS 1152                       // cols 0..1151 LDS-class
#define SP_TAU   424                        // stream threads (848 cols / 2)
#define SP_F4_PER_B 6784                    // 2*8*424 float4 per b
#define SMEM_MEGA (4096 + XPT_COLS * 128)   // 4KB wred + 147KB cols = 151552

__device__ __forceinline__ float clampf(float v, float lo, float hi) {
    return fminf(fmaxf(v, lo), hi);
}

__device__ __forceinline__ float softplusf(float v) {
    return (v > 20.f) ? v : log1pf(expf(v));
}

__device__ __forceinline__ float readlane_f(float v, int lane) {
    return __int_as_float(__builtin_amdgcn_readlane(__float_as_int(v), lane));
}

// streamP float4 index within one b: [j(col parity)][k(g-quad)][tau].
// For fixed (j,k) a wave's 64 lanes read 64 consecutive float4 = coalesced.
__device__ __forceinline__ int sp_idx(int tau, int j, int k) {
    return (j * 8 + k) * SP_TAU + tau;
}

// packed-byte yv helpers (g compile-time constant after unroll; yv<=205<256)
__device__ __forceinline__ int yget(const int* yvp, int g) {
    return (yvp[g >> 2] >> (8 * (g & 3))) & 0xff;
}
__device__ __forceinline__ void yadd(int* yvp, int g, int delta) {
    yvp[g >> 2] += delta << (8 * (g & 3));
}

// Fully-packed butterfly: reduce v[0..31] (per-g partials) across 64 lanes in
// 32 shuffles.  Returns the wave total for g = (lane>>1)&31 (dup on pairs).
__device__ __forceinline__ float wave_sum32(float v[NG], int lane) {
    {   const bool hi = (lane & 32) != 0;
        #pragma unroll
        for (int k = 0; k < 16; ++k) {
            float s = hi ? v[k] : v[k + 16];
            float r = __shfl_xor(s, 32);
            v[k] = (hi ? v[k + 16] : v[k]) + r;
        }
    }
    {   const bool hi = (lane & 16) != 0;
        #pragma unroll
        for (int k = 0; k < 8; ++k) {
            float s = hi ? v[k] : v[k + 8];
            float r = __shfl_xor(s, 16);
            v[k] = (hi ? v[k + 8] : v[k]) + r;
        }
    }
    {   const bool hi = (lane & 8) != 0;
        #pragma unroll
        for (int k = 0; k < 4; ++k) {
            float s = hi ? v[k] : v[k + 4];
            float r = __shfl_xor(s, 8);
            v[k] = (hi ? v[k + 4] : v[k]) + r;
        }
    }
    {   const bool hi = (lane & 4) != 0;
        #pragma unroll
        for (int k = 0; k < 2; ++k) {
            float s = hi ? v[k] : v[k + 2];
            float r = __shfl_xor(s, 4);
            v[k] = (hi ? v[k + 2] : v[k]) + r;
        }
    }
    {   const bool hi = (lane & 2) != 0;
        float s = hi ? v[0] : v[1];
        float r = __shfl_xor(s, 2);
        v[0] = (hi ? v[1] : v[0]) + r;
    }
    v[0] += __shfl_xor(v[0], 1);
    return v[0];
}

// ---- IPF path: 1024 thr (16 waves), thread owns cols c0, c0+1 ------------
__device__ __forceinline__ void ipf_path(
        const float* __restrict__ xpT, const float* __restrict__ spB,
        const int* __restrict__ tsum, float* __restrict__ out,
        char* smem, int b, int t) {
    const int lane = t & 63, w = t >> 6;       // 16 waves
    const bool lcls  = (t < 576);              // 9 waves: cols in LDS
    const bool valid = (t < 1000);
    const int g_own = (lane >> 1) & 31;
    const int rot = t & 7;
    const int tau = t - 576;                   // stream thread index
    const int c0 = lcls ? (2 * t) : (XPT_COLS + 2 * tau);

    float* wred = (float*)smem;                // [2][16][32] dbuf
    char* cb = smem + 4096 + (size_t)c0 * 128; // col c0 base; c0+1 at +128
    const float4* gx = (const float4*)(xpT + ((size_t)b * XPT_COLS + c0) * NG);
    const float4* gs = (const float4*)spB + (size_t)b * SP_F4_PER_B;

    float Cc0 = 0.f, Cc1 = 0.f;
    if (valid) {
        const int2 ci = *(const int2*)(tsum + (size_t)b * ND + c0);
        Cc0 = (float)ci.x; Cc1 = (float)ci.y;
    }
    float Ac0 = 1.f, Ac1 = 1.f;
    float Bown = 1.f, Rown;

    // prologue: load 2 cols, stash LDS-class (16B chunks rotated by
    // (k+rot)&7: lane quad = (k+lane)&7 -> 2 lanes/bank = conflict-free),
    // compute row anchors R (16-wave combine, r2 FP order).
    {
        float v[NG];
        if (lcls) {
            #pragma unroll
            for (int k = 0; k < 8; ++k) {
                const float4 a = gx[k], c = gx[8 + k];
                const int ro = 16 * ((k + rot) & 7);
                *(float4*)(cb + ro)       = a;
                *(float4*)(cb + 128 + ro) = c;
                v[4*k+0] = a.x + c.x;
                v[4*k+1] = a.y + c.y;
                v[4*k+2] = a.z + c.z;
                v[4*k+3] = a.w + c.w;
            }
        } else if (valid) {
            #pragma unroll
            for (int k = 0; k < 8; ++k) {
                const float4 a = gs[sp_idx(tau, 0, k)];
                const float4 c = gs[sp_idx(tau, 1, k)];
                v[4*k+0] = a.x + c.x;
                v[4*k+1] = a.y + c.y;
                v[4*k+2] = a.z + c.z;
                v[4*k+3] = a.w + c.w;
            }
        } else {
            #pragma unroll
            for (int g = 0; g < NG; ++g) v[g] = 0.f;
        }
        const float tot = wave_sum32(v, lane);
        if (!(lane & 1)) wred[w * NG + g_own] = tot;
        __syncthreads();
        float s = 0.f;
        #pragma unroll
        for (int w2 = 0; w2 < 16; ++w2) s += wred[w2 * NG + g_own];
        Rown = s;
    }

    // 60 IPF iterations, one barrier each (dbuf wred)
    for (int q = 1; q <= 60; ++q) {
        // ---- column pass: s(c) = sum_g y0[g,c] * B[g] ----
        float s0 = 0.f, s1 = 0.f;
        if (lcls) {
            #pragma unroll
            for (int k = 0; k < 8; ++k) {
                const int ro = 16 * ((k + rot) & 7);
                const float4 a = *(const float4*)(cb + ro);
                const float4 c = *(const float4*)(cb + 128 + ro);
                float bg;
                bg = readlane_f(Bown, 8*k+0); s0 += a.x*bg; s1 += c.x*bg;
                bg = readlane_f(Bown, 8*k+2); s0 += a.y*bg; s1 += c.y*bg;
                bg = readlane_f(Bown, 8*k+4); s0 += a.z*bg; s1 += c.z*bg;
                bg = readlane_f(Bown, 8*k+6); s0 += a.w*bg; s1 += c.w*bg;
            }
        } else if (valid) {
            #pragma unroll
            for (int k = 0; k < 8; ++k) {
                const float4 a = gs[sp_idx(tau, 0, k)];
                const float4 c = gs[sp_idx(tau, 1, k)];
                float bg;
                bg = readlane_f(Bown, 8*k+0); s0 += a.x*bg; s1 += c.x*bg;
                bg = readlane_f(Bown, 8*k+2); s0 += a.y*bg; s1 += c.y*bg;
                bg = readlane_f(Bown, 8*k+4); s0 += a.z*bg; s1 += c.z*bg;
                bg = readlane_f(Bown, 8*k+6); s0 += a.w*bg; s1 += c.w*bg;
            }
        }
        Ac0 *= clampf(Cc0 / fmaxf(Ac0 * s0, 1e-12f), 0.75f, 1.25f);
        Ac1 *= clampf(Cc1 / fmaxf(Ac1 * s1, 1e-12f), 0.75f, 1.25f);

        asm volatile("" ::: "memory");   // keep passes separate (reg pressure)

        // ---- row pass: v[g] = y0[g,c0]*A[c0] + y0[g,c1]*A[c1] ----
        float v[NG];
        if (lcls) {
            #pragma unroll
            for (int k = 0; k < 8; ++k) {
                const int ro = 16 * ((k + rot) & 7);
                const float4 a = *(const float4*)(cb + ro);
                const float4 c = *(const float4*)(cb + 128 + ro);
                v[4*k+0] = a.x * Ac0 + c.x * Ac1;
                v[4*k+1] = a.y * Ac0 + c.y * Ac1;
                v[4*k+2] = a.z * Ac0 + c.z * Ac1;
                v[4*k+3] = a.w * Ac0 + c.w * Ac1;
            }
        } else if (valid) {
            #pragma unroll
            for (int k = 0; k < 8; ++k) {
                const float4 a = gs[sp_idx(tau, 0, k)];
                const float4 c = gs[sp_idx(tau, 1, k)];
                v[4*k+0] = a.x * Ac0 + c.x * Ac1;
                v[4*k+1] = a.y * Ac0 + c.y * Ac1;
                v[4*k+2] = a.z * Ac0 + c.z * Ac1;
                v[4*k+3] = a.w * Ac0 + c.w * Ac1;
            }
        } else {
            #pragma unroll
            for (int g = 0; g < NG; ++g) v[g] = 0.f;
        }
        const float tot = wave_sum32(v, lane);
        const int buf = (q & 1) * (16 * NG);
        if (!(lane & 1)) wred[buf + w * NG + g_own] = tot;
        __syncthreads();
        float s = 0.f;
        #pragma unroll
        for (int w2 = 0; w2 < 16; ++w2) s += wred[buf + w2 * NG + g_own];
        Bown *= clampf(Rown / fmaxf(Bown * s, 1e-12f), 0.75f, 1.25f);
    }

    // park A finals in out's g=0 row (positions each k_epi thread reads then
    // overwrites itself) and B finals as 8 replicas at 250-col boundaries in
    // the g=1 row (each k_epi block reads the replica inside its OWN range
    // before its first write; r7-proven scheme).
    if (valid) {
        float* ap = out + 1 + (size_t)(b * NG) * ND + c0;
        ap[0] = Ac0; ap[1] = Ac1;
    }
    if (w == 0 && !(lane & 1)) {
        #pragma unroll
        for (int qq = 0; qq < 8; ++qq)
            out[1 + (size_t)(b * NG + 1) * ND + qq * 250 + g_own] = Bown;
    }
}

// ---- loss-partials path: 1024 thr = two 512-halves (r2-verbatim) ---------
__device__ __forceinline__ void loss_path(
        const float* __restrict__ x, const float* __restrict__ nl,
        const float* __restrict__ tgt, const float* __restrict__ W,
        const float* __restrict__ bias, float* __restrict__ res2,
        float* smem, int cx, int b, int tt) {
    const int half = cx & 1;
    float* xsl = smem;                         // 256 (shared across halves)
    float* nsl = smem + 256;                   // 256 (shared across halves)
    float* tgl = smem + 512 + half * 4284;     // 252 per half
    float* pt  = tgl + 252;                    // 16 x 252 per half

    if (half == 0 && tt < 256) {               // == global t < 256
        const float* xb = x + (size_t)b * NG * NDIN;
        float s = 0.f;
        for (int g = 0; g < NG; ++g) s += xb[g * NDIN + tt];
        xsl[tt] = s;
        const float* nb = nl + (size_t)b * NG * (NM * NE);
        float s2 = 0.f;
        for (int g = 0; g < NG; ++g) s2 += nb[g * (NM * NE) + tt];
        nsl[tt] = s2;
    }

    int tm = 0, tn = 0;
    if (tt >= 16 && tt < 152) {
        int p = tt - 16;
        for (int m = 0; m < NM; ++m) {
            int c = NM - m;
            if (p < c) { tm = m; tn = m + p; break; }
            p -= c;
        }
    }
    __syncthreads();

    const int d = cx * 250 + tt;
    if (tt < 250) {
        tgl[tt] = tgt[b * ND + d];
        float xw = 0.f;
        #pragma unroll 8
        for (int k = 0; k < NDIN; ++k) xw += xsl[k] * W[(size_t)k * ND + d];
        float we[NE];
        #pragma unroll
        for (int e = 0; e < NE; ++e) we[e] = W[(size_t)(NDIN + e) * ND + d];
        const float base0 = xw + (float)NG * bias[d];
        #pragma unroll
        for (int m = 0; m < NM; ++m) {
            float pm = base0;
            #pragma unroll
            for (int e = 0; e < NE; ++e) pm += nsl[m * NE + e] * we[e];
            pt[m * 252 + tt] = pm;
        }
    }
    if (tt < 32) {                     // zero-pad cols 250,251
        pt[(tt >> 1) * 252 + 250 + (tt & 1)] = 0.f;
        if (tt < 2) tgl[250 + tt] = 0.f;
    }
    __syncthreads();

    float acc = 0.f;
    if (tt < 16) {
        const float4* pa  = (const float4*)&pt[tt * 252];
        const float4* tga = (const float4*)&tgl[0];
        for (int i = 0; i < 63; ++i) {
            float4 pv = pa[i], tv = tga[i];
            float e0 = pv.x - tv.x, e1 = pv.y - tv.y, e2 = pv.z - tv.z, e3 = pv.w - tv.w;
            acc += e0 * e0 + e1 * e1 + e2 * e2 + e3 * e3;
        }
    } else if (tt < 152) {
        const float4* pa = (const float4*)&pt[tm * 252];
        const float4* pb = (const float4*)&pt[tn * 252];
        for (int i = 0; i < 63; ++i) {
            float4 u = pa[i], v = pb[i];
            acc += u.x * v.x + u.y * v.y + u.z * v.z + u.w * v.w;
        }
    }
    if (tt < 152) res2[((size_t)b * 8 + cx) * 152 + tt] = acc;
}

extern "C" __global__ __launch_bounds__(1024)
void mega(const float* __restrict__ x, const float* __restrict__ nl,
          const float* __restrict__ tgt, const float* __restrict__ W,
          const float* __restrict__ bias, const float* __restrict__ xpT,
          const float* __restrict__ spB, const int* __restrict__ tsum,
          float* __restrict__ out, float* __restrict__ res2) {
    extern __shared__ char smem[];     // 151552 B
    const int bid = blockIdx.x;        // 0..255 (1 block/CU)
    const int t = threadIdx.x;
    if (bid < NB) {
        ipf_path(xpT, spB, tsum, out, smem, bid, t);
    } else {
        const int l = bid - NB;        // 0..191; 256 slots, 2 halves each
        #pragma unroll
        for (int rep = 0; rep < 2; ++rep) {
            const int slot = l + rep * 192;
            if (slot < 256) {
                __syncthreads();
                const int cx = ((slot & 3) << 1) | (t >> 9);
                loss_path(x, nl, tgt, W, bias, res2, (float*)smem,
                          cx, slot >> 2, t & 511);
            }
        }
    }
}

// ---------------------------------------------------------------------------
// K_EPI: r7-proven register-resident integerization, one col/thread.
//   c32[32] in-place (col->z->frac), yv packed 4 B/dword in 8 VGPRs ->
//   ~50 live regs, spill-free at any allocator budget (r7 measured).
// Grid (8 chunks, 64 b) x 256 thr (250 active).  Reads B replica (own
// 250-range) + A[c] (own col) from `out`, barrier, then overwrites out.
// ---------------------------------------------------------------------------
extern "C" __global__ __launch_bounds__(256)
void k_epi(const float* __restrict__ xpT, const float* __restrict__ spB,
           const int* __restrict__ tsum, float* __restrict__ out) {
    const int chunk = blockIdx.x;      // 0..7
    const int b     = blockIdx.y;      // 0..63
    const int tt    = threadIdx.x;     // 0..255
    __shared__ float bf[NG];

    if (tt < NG)
        bf[tt] = out[1 + (size_t)(b * NG + 1) * ND + chunk * 250 + tt];
    __syncthreads();
    if (tt >= 250) return;

    const int c = chunk * 250 + tt;
    const float A = out[1 + (size_t)(b * NG) * ND + c];
    const int Ci = tsum[(size_t)b * ND + c];
    const float Cf = (float)Ci;

    // load column into registers (static indexing)
    float c32[NG];
    if (c < XPT_COLS) {
        const float4* cp = (const float4*)(xpT + ((size_t)b * XPT_COLS + c) * NG);
        #pragma unroll
        for (int k = 0; k < 8; ++k) {
            const float4 v = cp[k];
            c32[4*k+0] = v.x; c32[4*k+1] = v.y;
            c32[4*k+2] = v.z; c32[4*k+3] = v.w;
        }
    } else {
        const float4* gsp = (const float4*)spB + (size_t)b * SP_F4_PER_B;
        const int cc = c - XPT_COLS;
        const int tau2 = cc >> 1, j = cc & 1;
        #pragma unroll
        for (int k = 0; k < 8; ++k) {
            const float4 v = gsp[sp_idx(tau2, j, k)];
            c32[4*k+0] = v.x; c32[4*k+1] = v.y;
            c32[4*k+2] = v.z; c32[4*k+3] = v.w;
        }
    }

    // pass 1: z = (y0*A)*B, accumulate s (g ascending, proven FP order)
    float s = 0.f;
    #pragma unroll
    for (int g = 0; g < NG; ++g) {
        const float z = c32[g] * A * bf[g];
        s += z;
        c32[g] = z;
    }
    const float F = Cf / fmaxf(s, 1e-12f);

    // pass 2: floor/frac/yv (packed), isum
    int yvp[8];
    #pragma unroll
    for (int i = 0; i < 8; ++i) yvp[i] = 0;
    int isum = 0;
    #pragma unroll
    for (int g = 0; g < NG; ++g) {
        const float y = c32[g] * F;
        const float fl = floorf(y);
        const int yi = (int)fl;
        c32[g] = y - fl;              // frac, in place
        yadd(yvp, g, yi);
        isum += yi;
    }
    const int need = Ci - isum;
    const int pos = max(need, 0);
    const int qv = pos >> 5;
    const int rr = pos & 31;
    if (qv > 0) {
        #pragma unroll
        for (int i = 0; i < 8; ++i) yvp[i] += qv * 0x01010101;
    }
    #pragma unroll
    for (int g = 0; g < NG; ++g) {     // stable DESCENDING rank on frac
        const float fg = c32[g];
        int rank = 0;
        #pragma unroll
        for (int h = 0; h < NG; ++h) {
            if (h == g) continue;
            const float fh = c32[h];
            rank += (h < g) ? (fh >= fg ? 1 : 0) : (fh > fg ? 1 : 0);
        }
        if (rank < rr) yadd(yvp, g, 1);
    }
    // negative residual: one-shot ascending rank among yv>0 (== reference)
    int neg = max(-need, 0);
    neg = min(neg, isum);
    if (__builtin_expect(neg > 0, 0)) {
        const int q2 = neg >> 5;
        int removed = 0;
        #pragma unroll
        for (int g = 0; g < NG; ++g) {
            const int yb = yget(yvp, g);
            const int yn = max(yb - q2, 0);
            removed += yb - yn;
            yadd(yvp, g, yn - yb);
        }
        const int r2 = neg - removed;
        if (r2 > 0) {
            const float INF = __builtin_inff();
            #pragma unroll
            for (int g = 0; g < NG; ++g) {
                const float fg = (yget(yvp, g) > 0) ? c32[g] : INF;
                int rank = 0;
                #pragma unroll
                for (int h = 0; h < NG; ++h) {
                    if (h == g) continue;
                    const float fh = (yget(yvp, h) > 0) ? c32[h] : INF;
                    rank += (h < g) ? (fh <= fg ? 1 : 0) : (fh < fg ? 1 : 0);
                }
                if (rank < r2) {
                    const int yb = yget(yvp, g);
                    yadd(yvp, g, max(yb - 1, 0) - yb);
                }
            }
        }
    }
    #pragma unroll
    for (int g = 0; g < NG; ++g)
        out[1 + (size_t)(b * NG + g) * ND + c] = (float)yget(yvp, g);
}

// K2b: combine the 8 d-chunk partials per b and accumulate the loss.
extern "C" __global__ __launch_bounds__(64)
void k2b_combine(const float* __restrict__ res2, float* __restrict__ out) {
    const int b = blockIdx.x, t = threadIdx.x;
    __shared__ float res[152];
    for (int tau = t; tau < 152; tau += 64) {
        float s = 0.f;
        #pragma unroll
        for (int c = 0; c < 8; ++c) s += res2[((size_t)b * 8 + c) * 152 + tau];
        res[tau] = s;
    }
    __syncthreads();
    if (t == 0) {
        float conf = 0.f;
        for (int m = 0; m < NM; ++m) conf += sqrtf(res[m]);
        conf *= (1.f / NM);
        float pd = 0.f;
        for (int m = 0; m < NM; ++m) {
            const int offm = 16 + m * NM - m * (m - 1) / 2;
            const float sqm = res[offm];
            for (int n = m + 1; n < NM; ++n) {
                const int offn = 16 + n * NM - n * (n - 1) / 2;
                const float sqn = res[offn];
                const float inn = res[offm + (n - m)];
                pd += sqrtf(fmaxf(sqm + sqn - 2.f * inn, 1e-6f));
            }
        }
        pd = 2.f * pd / (float)(NM * (NM - 1));
        atomicAdd(out, (conf - 0.5f * pd) * (1.f / NB));
    }
}

// ---------------------------------------------------------------------------
// K3: x_pred = softplus(concat(x, noise_sample) @ W + bias); cols < 1152 to
// xpT [b][c][g], cols >= 1152 to the coalesced streamP layout.  Also zeroes
// out[0] (loss accumulator) - replaces the memset node.
// ---------------------------------------------------------------------------
extern "C" __global__ __launch_bounds__(256)
void k3_xpred(const float* __restrict__ x, const float* __restrict__ nsamp,
              const float* __restrict__ W, const float* __restrict__ bias,
              float* __restrict__ xpT, float* __restrict__ spB,
              float* __restrict__ out) {
    const int dx = blockIdx.x;     // 0..1
    const int rb = blockIdx.y;     // 0..255
    const int t  = threadIdx.x;
    if (dx == 0 && rb == 0 && t == 0) out[0] = 0.f;   // loss accumulator init
    __shared__ float xr[8][NK];
    #pragma unroll
    for (int r = 0; r < 8; ++r) {
        const int row = rb * 8 + r;
        xr[r][t] = x[(size_t)row * NDIN + t];
        if (t < NE) xr[r][NDIN + t] = nsamp[row * NE + t];
    }
    __syncthreads();
    if (t >= 250) return;
    const int d = dx * 1000 + 4 * t;
    float acc[8][4];
    #pragma unroll
    for (int r = 0; r < 8; ++r) {
        acc[r][0] = 0.f; acc[r][1] = 0.f; acc[r][2] = 0.f; acc[r][3] = 0.f;
    }
    for (int k = 0; k < NK; k += 4) {
        float4 w[4];
        #pragma unroll
        for (int kk = 0; kk < 4; ++kk) w[kk] = *(const float4*)&W[(size_t)(k + kk) * ND + d];
        #pragma unroll
        for (int r = 0; r < 8; ++r) {
            const float4 xv = *(const float4*)&xr[r][k];
            acc[r][0] += xv.x * w[0].x + xv.y * w[1].x + xv.z * w[2].x + xv.w * w[3].x;
            acc[r][1] += xv.x * w[0].y + xv.y * w[1].y + xv.z * w[2].y + xv.w * w[3].y;
            acc[r][2] += xv.x * w[0].z + xv.y * w[1].z + xv.z * w[2].z + xv.w * w[3].z;
            acc[r][3] += xv.x * w[0].w + xv.y * w[1].w + xv.z * w[2].w + xv.w * w[3].w;
        }
    }
    const float4 bv = *(const float4*)&bias[d];
    const float bvv[4] = {bv.x, bv.y, bv.z, bv.w};
    const int b2 = rb >> 2;            // b = row/32
    const int g0 = (rb & 3) * 8;       // this block's 8-g slice
    #pragma unroll
    for (int dd = 0; dd < 4; ++dd) {
        const int dc = d + dd;
        float4 lo, hi;
        lo.x = softplusf(acc[0][dd] + bvv[dd]);
        lo.y = softplusf(acc[1][dd] + bvv[dd]);
        lo.z = softplusf(acc[2][dd] + bvv[dd]);
        lo.w = softplusf(acc[3][dd] + bvv[dd]);
        hi.x = softplusf(acc[4][dd] + bvv[dd]);
        hi.y = softplusf(acc[5][dd] + bvv[dd]);
        hi.z = softplusf(acc[6][dd] + bvv[dd]);
        hi.w = softplusf(acc[7][dd] + bvv[dd]);
        if (dc < XPT_COLS) {
            float* op = xpT + ((size_t)b2 * XPT_COLS + dc) * NG + g0;
            *(float4*)op       = lo;
            *(float4*)(op + 4) = hi;
        } else {
            float4* sp = (float4*)spB + (size_t)b2 * SP_F4_PER_B;
            const int cc = dc - XPT_COLS;
            const int tau2 = cc >> 1, j = cc & 1;
            const int kk = g0 >> 2;
            sp[sp_idx(tau2, j, kk)]     = lo;
            sp[sp_idx(tau2, j, kk + 1)] = hi;
        }
    }
}

// ---------------------------------------------------------------------------
extern "C" void kernel_launch(void* const* d_in, const int* in_sizes, int n_in,
                              void* d_out, int out_size, void* d_ws, size_t ws_size,
                              hipStream_t stream) {
    const float* x     = (const float*)d_in[0];
    const float* tgt   = (const float*)d_in[1];
    const int*   tsum  = (const int*)d_in[2];
    const float* W     = (const float*)d_in[3];
    const float* bias  = (const float*)d_in[4];
    const float* nl    = (const float*)d_in[5];
    const float* nsamp = (const float*)d_in[6];
    float* out = (float*)d_out;

    (void)in_sizes; (void)n_in; (void)out_size; (void)ws_size;

    // ws layout (total 16,695,296 B == proven footprint):
    //   xpT:     64 * 1152 cols * 32 g * 4 B  =  9,437,184
    //   streamP: 64 * 6784 float4 * 16 B      =  6,946,816   (sum 16,384,000)
    //   res2:    64 * 8 * 152 * 4 B           =    311,296
    float* xpT  = (float*)d_ws;
    float* spB  = (float*)((char*)d_ws + 9437184);
    float* res2 = (float*)((char*)d_ws + 16384000);

    static int s_attr_done = 0;
    if (!s_attr_done) {
        hipFuncSetAttribute(reinterpret_cast<const void*>(mega),
                            hipFuncAttributeMaxDynamicSharedMemorySize,
                            SMEM_MEGA);
        s_attr_done = 1;
    }

    hipLaunchKernelGGL(k3_xpred, dim3(2, 256), dim3(256), 0, stream,
                       x, nsamp, W, bias, xpT, spB, out);
    hipLaunchKernelGGL(mega, dim3(256), dim3(1024), SMEM_MEGA, stream,
                       x, nl, tgt, W, bias, xpT, spB, tsum, out, res2);
    hipLaunchKernelGGL(k_epi, dim3(8, 64), dim3(256), 0, stream,
                       xpT, spB, tsum, out);
    hipLaunchKernelGGL(k2b_combine, dim3(NB), dim3(64), 0, stream, res2, out);
}